// Round 1
// baseline (149.292 us; speedup 1.0000x reference)
//
#include <hip/hip_runtime.h>
#include <hip/hip_bf16.h>
#include <math.h>

#define NA 2048   // agents (2^11)
#define TT 20     // timesteps
#define KK 32     // neighbors
#define CC 32     // in channels
#define OO 64     // out channels / hidden
#define GG 256    // 4*OO gates

typedef __attribute__((ext_vector_type(8))) short short8;
typedef __attribute__((ext_vector_type(4))) float float4v;

__device__ __forceinline__ float fast_rcp(float x) {
    return __builtin_amdgcn_rcpf(x);
}
__device__ __forceinline__ float sigm(float x) {
    return fast_rcp(1.f + __expf(-x));
}
__device__ __forceinline__ float tanh_fast(float x) {
    return 1.f - 2.f * fast_rcp(1.f + __expf(2.f * x));
}
// bf16 RNE on raw bits (ties-to-even; NaN not expected here).
__device__ __forceinline__ unsigned cvt_rne(float f) {
    unsigned u = __float_as_uint(f);
    return (u + 0x7FFFu + ((u >> 16) & 1u)) >> 16;
}
__device__ __forceinline__ unsigned pack2(float a, float b) {
    return cvt_rne(a) | (cvt_rne(b) << 16);
}
__device__ __forceinline__ float bf_lo(unsigned u) {
    return __uint_as_float(u << 16);
}
__device__ __forceinline__ float bf_hi(unsigned u) {
    return __uint_as_float(u & 0xffff0000u);
}

// P[t][n][o] = sum_c x[n][t][c] * conv_w[o][c], stored bf16 (128B rows).
// Block 0 pre-converts w_ih/w_hh to bf16 and precomputes the folded gate
// bias (b_ih + b_hh + conv_b @ w_ih^T).
__global__ __launch_bounds__(256) void proj_kernel(
    const float* __restrict__ x, const float* __restrict__ conv_w,
    const float* __restrict__ conv_b, const float* __restrict__ w_ih,
    const float* __restrict__ w_hh, const float* __restrict__ b_ih,
    const float* __restrict__ b_hh,
    __hip_bfloat16* __restrict__ P, unsigned short* __restrict__ wihb,
    unsigned short* __restrict__ whhb, float* __restrict__ biasT)
{
    const int tid = threadIdx.x;
    if (blockIdx.x == 0) {   // prep block
        for (int e = tid; e < 4 * OO * OO; e += 256) {
            wihb[e] = (unsigned short)cvt_rne(w_ih[e]);
            whhb[e] = (unsigned short)cvt_rne(w_hh[e]);
        }
        float bj = b_ih[tid] + b_hh[tid];
        #pragma unroll
        for (int o = 0; o < OO; o += 4) {
            float4 cb = *(const float4*)(conv_b + o);
            float4 wr = *(const float4*)(w_ih + (size_t)tid * OO + o);
            bj = fmaf(cb.x, wr.x, bj); bj = fmaf(cb.y, wr.y, bj);
            bj = fmaf(cb.z, wr.z, bj); bj = fmaf(cb.w, wr.w, bj);
        }
        biasT[tid] = bj;
        return;
    }
    const int lane = tid & 63;
    const int wv = tid >> 6;
    float w[CC];
    #pragma unroll
    for (int c = 0; c < CC; c += 4) {
        float4 v = *(const float4*)(conv_w + lane * CC + c);
        w[c] = v.x; w[c + 1] = v.y; w[c + 2] = v.z; w[c + 3] = v.w;
    }
    const int rbase = (blockIdx.x - 1) * 16 + wv * 4;
    #pragma unroll
    for (int i = 0; i < 4; ++i) {
        int r = rbase + i;                    // r = n*TT + t (x row order)
        const float* xr = x + (size_t)r * CC;
        float a0 = 0.f, a1 = 0.f;
        #pragma unroll
        for (int c = 0; c < CC; c += 8) {
            float4 v = *(const float4*)(xr + c);
            float4 u = *(const float4*)(xr + c + 4);
            a0 = fmaf(v.x, w[c], a0);     a0 = fmaf(v.y, w[c + 1], a0);
            a0 = fmaf(v.z, w[c + 2], a0); a0 = fmaf(v.w, w[c + 3], a0);
            a1 = fmaf(u.x, w[c + 4], a1); a1 = fmaf(u.y, w[c + 5], a1);
            a1 = fmaf(u.z, w[c + 6], a1); a1 = fmaf(u.w, w[c + 7], a1);
        }
        int n = r / TT;
        int t = r - n * TT;
        ((unsigned short*)P)[(((size_t)t << 11) + n) * OO + lane] =
            (unsigned short)cvt_rne(a0 + a1);
    }
}

// FUSED gather + LSTM. Per block: 16 agents, 4 waves (wave = gate plane).
// The neighbor gather-max for step t+1 (32 random L2 rows/thread + 128
// fmax) is issued at the top of step t and reduced in the two slack
// regions (after the gp writes / after the pointwise), so its L2 latency
// hides under the serial recurrence. A-index rows are double-buffered in
// LDS two steps ahead; gathered feat rows are double-buffered in LDS as
// bf16 with 144B row stride (16B-aligned ds_read_b128 frags, 8 distinct
// start-bank groups -> bank-floor reads).
__global__ __launch_bounds__(256, 2) void lstm_fused_kernel(
    const __hip_bfloat16* __restrict__ P, const int* __restrict__ A,
    const unsigned short* __restrict__ wihb,
    const unsigned short* __restrict__ whhb,
    const float* __restrict__ biasT, float* __restrict__ out)
{
    const int tid = threadIdx.x;
    const int lane = tid & 63;
    const int wv = tid >> 6;          // gate plane
    const int l15 = lane & 15;
    const int q = lane >> 4;
    const int a0 = blockIdx.x * 16;
    const int a = tid >> 4;           // pointwise/gather: agent 0..15
    const int c0 = (tid & 15) * 4;    // pointwise: first channel
    const int oc8 = tid & 15;         // gather: 8B chunk (4 channels)

    // B-frags: rows wv*64+ch of w_ih and w_hh (bf16, preconverted)
    short8 bfI[4][2], bfH[4][2];
    #pragma unroll
    for (int tt2 = 0; tt2 < 4; ++tt2) {
        int row = wv * 64 + tt2 * 16 + l15;
        #pragma unroll
        for (int ks = 0; ks < 2; ++ks) {
            bfI[tt2][ks] =
                *(const short8*)(wihb + ((size_t)row << 6) + ks * 32 + q * 8);
            bfH[tt2][ks] =
                *(const short8*)(whhb + ((size_t)row << 6) + ks * 32 + q * 8);
        }
    }
    float4 bias4[4];
    #pragma unroll
    for (int g = 0; g < 4; ++g)
        bias4[g] = *(const float4*)(biasT + g * 64 + c0);

    __shared__ __align__(16) unsigned short h_sh[16 * 72];     // bf16, pad
    __shared__ float gp[4][16][68];                            // gate planes
    __shared__ int A_sh[2][16 * KK];                           // idx dbuf
    __shared__ __align__(16) unsigned short feat_sh[2][16][72];// feat dbuf

    // stage A[0] and A[1] (contiguous 2KB per slab for this agent range)
    #pragma unroll
    for (int b = 0; b < 2; ++b)
        ((int2*)A_sh[b])[tid] =
            ((const int2*)(A + ((size_t)b * NA + a0) * KK))[tid];

    {   // h = 0
        uint2 z; z.x = 0u; z.y = 0u;
        *(uint2*)&h_sh[a * 72 + c0] = z;
    }
    float cst[4] = {0.f, 0.f, 0.f, 0.f};

    __syncthreads();  // A_sh + h_sh ready

    const unsigned short* Pb = (const unsigned short*)P;

    // prologue: full gather of slab 0 -> feat_sh[0]
    {
        const char* plane = (const char*)Pb + oc8 * 8;
        const int* myA = &A_sh[0][a * KK];
        float m0 = -INFINITY, m1 = -INFINITY, m2 = -INFINITY, m3 = -INFINITY;
        #pragma unroll
        for (int bb = 0; bb < 2; ++bb) {
            int idx[16];
            #pragma unroll
            for (int g = 0; g < 16; ++g)
                idx[g] = myA[bb * 16 + g];
            uint2 uv[16];
            #pragma unroll
            for (int g = 0; g < 16; ++g)
                uv[g] = *(const uint2*)(plane + ((size_t)idx[g] << 7));
            #pragma unroll
            for (int g = 0; g < 16; ++g) {
                m0 = fmaxf(m0, bf_lo(uv[g].x)); m1 = fmaxf(m1, bf_hi(uv[g].x));
                m2 = fmaxf(m2, bf_lo(uv[g].y)); m3 = fmaxf(m3, bf_hi(uv[g].y));
            }
        }
        uint2 su = *(const uint2*)(plane + ((size_t)(a0 + a) << 7));
        uint2 pk;
        pk.x = pack2(m0 - bf_lo(su.x), m1 - bf_hi(su.x));
        pk.y = pack2(m2 - bf_lo(su.y), m3 - bf_hi(su.y));
        *(uint2*)&feat_sh[0][a][oc8 * 4] = pk;
    }

    for (int t = 0; t < TT; ++t) {
        __syncthreads();  // h_sh + feat_sh[t&1] ready

        // ---- issue gather for slab t+1 (reduced later; latency hidden)
        const int tg = (t + 1 < TT) ? t + 1 : TT - 1;
        const char* plane =
            (const char*)(Pb + ((size_t)tg << 17)) + oc8 * 8;
        const int* myA = &A_sh[(t + 1) & 1][a * KK];
        int idx1[16], idx2[16];
        #pragma unroll
        for (int g = 0; g < 16; ++g) idx1[g] = myA[g];
        #pragma unroll
        for (int g = 0; g < 16; ++g) idx2[g] = myA[16 + g];
        uint2 uv1[16], uv2[16];
        #pragma unroll
        for (int g = 0; g < 16; ++g)
            uv1[g] = *(const uint2*)(plane + ((size_t)idx1[g] << 7));
        #pragma unroll
        for (int g = 0; g < 16; ++g)
            uv2[g] = *(const uint2*)(plane + ((size_t)idx2[g] << 7));
        uint2 su = *(const uint2*)(plane + ((size_t)(a0 + a) << 7));
        // early-issue next A slab load (ds_write after gp writes)
        const int ts = (t + 2 < TT) ? t + 2 : TT - 1;
        int2 av = ((const int2*)(A + ((size_t)ts * NA + a0) * KK))[tid];

        // ---- MFMA phase: gates = feat @ w_ih^T + h @ w_hh^T
        float4v acc[4] = {{0.f, 0.f, 0.f, 0.f}, {0.f, 0.f, 0.f, 0.f},
                          {0.f, 0.f, 0.f, 0.f}, {0.f, 0.f, 0.f, 0.f}};
        #pragma unroll
        for (int ks = 0; ks < 2; ++ks) {
            short8 ffk =
                *(const short8*)&feat_sh[t & 1][l15][ks * 32 + q * 8];
            short8 ah = *(const short8*)(&h_sh[l15 * 72 + ks * 32 + q * 8]);
            #pragma unroll
            for (int tt2 = 0; tt2 < 4; ++tt2) {
                acc[tt2] = __builtin_amdgcn_mfma_f32_16x16x32_bf16(
                    ffk, bfI[tt2][ks], acc[tt2], 0, 0, 0);
                acc[tt2] = __builtin_amdgcn_mfma_f32_16x16x32_bf16(
                    ah, bfH[tt2][ks], acc[tt2], 0, 0, 0);
            }
        }
        #pragma unroll
        for (int tt2 = 0; tt2 < 4; ++tt2)
            #pragma unroll
            for (int rg = 0; rg < 4; ++rg)
                gp[wv][q * 4 + rg][tt2 * 16 + l15] = acc[tt2][rg];

        // A slab -> LDS (other buffer than the one read this step)
        ((int2*)A_sh[t & 1])[tid] = av;

        // ---- reduce gather batch 1 while gp settles
        float m0 = -INFINITY, m1 = -INFINITY, m2 = -INFINITY, m3 = -INFINITY;
        #pragma unroll
        for (int g = 0; g < 16; ++g) {
            m0 = fmaxf(m0, bf_lo(uv1[g].x)); m1 = fmaxf(m1, bf_hi(uv1[g].x));
            m2 = fmaxf(m2, bf_lo(uv1[g].y)); m3 = fmaxf(m3, bf_hi(uv1[g].y));
        }
        __syncthreads();  // gp ready

        float4 gv0 = *(const float4*)&gp[0][a][c0];
        float4 gv1 = *(const float4*)&gp[1][a][c0];
        float4 gv2 = *(const float4*)&gp[2][a][c0];
        float4 gv3 = *(const float4*)&gp[3][a][c0];
        float hv[4];
        {
            float gi[4] = {gv0.x + bias4[0].x, gv0.y + bias4[0].y,
                           gv0.z + bias4[0].z, gv0.w + bias4[0].w};
            float gf[4] = {gv1.x + bias4[1].x, gv1.y + bias4[1].y,
                           gv1.z + bias4[1].z, gv1.w + bias4[1].w};
            float gz[4] = {gv2.x + bias4[2].x, gv2.y + bias4[2].y,
                           gv2.z + bias4[2].z, gv2.w + bias4[2].w};
            float go[4] = {gv3.x + bias4[3].x, gv3.y + bias4[3].y,
                           gv3.z + bias4[3].z, gv3.w + bias4[3].w};
            #pragma unroll
            for (int e = 0; e < 4; ++e) {
                float ig = sigm(gi[e]);
                float fg = sigm(gf[e]);
                float zg = tanh_fast(gz[e]);
                float og = sigm(go[e]);
                cst[e] = fmaf(fg, cst[e], ig * zg);
                hv[e] = og * tanh_fast(cst[e]);
            }
        }
        {
            uint2 pk;
            pk.x = pack2(hv[0], hv[1]);
            pk.y = pack2(hv[2], hv[3]);
            *(uint2*)&h_sh[a * 72 + c0] = pk;
        }
        float4 ho; ho.x = hv[0]; ho.y = hv[1]; ho.z = hv[2]; ho.w = hv[3];
        *(float4*)(out + (((size_t)(a0 + a) * TT + t) << 6) + c0) = ho;
        if (t == TT - 1) {
            size_t hb = (size_t)NA * TT * OO;
            *(float4*)(out + hb + ((size_t)(a0 + a) << 6) + c0) = ho;
            float4 co; co.x = cst[0]; co.y = cst[1]; co.z = cst[2]; co.w = cst[3];
            *(float4*)(out + hb + ((size_t)NA << 6) + ((size_t)(a0 + a) << 6) + c0) = co;
        }

        // ---- reduce gather batch 2 + publish feat[t+1]
        #pragma unroll
        for (int g = 0; g < 16; ++g) {
            m0 = fmaxf(m0, bf_lo(uv2[g].x)); m1 = fmaxf(m1, bf_hi(uv2[g].x));
            m2 = fmaxf(m2, bf_lo(uv2[g].y)); m3 = fmaxf(m3, bf_hi(uv2[g].y));
        }
        uint2 pk;
        pk.x = pack2(m0 - bf_lo(su.x), m1 - bf_hi(su.x));
        pk.y = pack2(m2 - bf_lo(su.y), m3 - bf_hi(su.y));
        *(uint2*)&feat_sh[(t + 1) & 1][a][oc8 * 4] = pk;
    }
}

extern "C" void kernel_launch(void* const* d_in, const int* in_sizes, int n_in,
                              void* d_out, int out_size, void* d_ws, size_t ws_size,
                              hipStream_t stream) {
    const float* x      = (const float*)d_in[0];
    const int*   A      = (const int*)  d_in[1];
    const float* conv_w = (const float*)d_in[2];
    const float* conv_b = (const float*)d_in[3];
    const float* w_ih   = (const float*)d_in[4];
    const float* w_hh   = (const float*)d_in[5];
    const float* b_ih   = (const float*)d_in[6];
    const float* b_hh   = (const float*)d_in[7];
    float* out = (float*)d_out;

    char* ws = (char*)d_ws;
    __hip_bfloat16* P  = (__hip_bfloat16*)ws;                    // 5.25 MB
    size_t offW = (size_t)TT * NA * OO * 2;
    unsigned short* wihb = (unsigned short*)(ws + offW);         // 32 KB
    unsigned short* whhb = wihb + 4 * OO * OO;                   // 32 KB
    float* biasT = (float*)(whhb + 4 * OO * OO);                 // 1 KB

    hipLaunchKernelGGL(proj_kernel, dim3(NA * TT / 16 + 1), dim3(256), 0, stream,
                       x, conv_w, conv_b, w_ih, w_hh, b_ih, b_hh,
                       P, wihb, whhb, biasT);
    hipLaunchKernelGGL(lstm_fused_kernel, dim3(NA / 16), dim3(256), 0, stream,
                       P, A, wihb, whhb, biasT, out);
}

// Round 2
// 129.809 us; speedup vs baseline: 1.1501x; 1.1501x over previous
//
#include <hip/hip_runtime.h>
#include <hip/hip_bf16.h>
#include <math.h>

#define NA 2048   // agents (2^11)
#define TT 20     // timesteps
#define KK 32     // neighbors
#define CC 32     // in channels
#define OO 64     // out channels / hidden
#define GG 256    // 4*OO gates

typedef __attribute__((ext_vector_type(8))) short short8;
typedef __attribute__((ext_vector_type(4))) float float4v;

__device__ __forceinline__ float fast_rcp(float x) {
    return __builtin_amdgcn_rcpf(x);
}
__device__ __forceinline__ float sigm(float x) {
    return fast_rcp(1.f + __expf(-x));
}
__device__ __forceinline__ float tanh_fast(float x) {
    return 1.f - 2.f * fast_rcp(1.f + __expf(2.f * x));
}
// bf16 RNE on raw bits (ties-to-even; NaN not expected here).
__device__ __forceinline__ unsigned cvt_rne(float f) {
    unsigned u = __float_as_uint(f);
    return (u + 0x7FFFu + ((u >> 16) & 1u)) >> 16;
}
__device__ __forceinline__ unsigned pack2(float a, float b) {
    return cvt_rne(a) | (cvt_rne(b) << 16);
}
__device__ __forceinline__ float bf_lo(unsigned u) {
    return __uint_as_float(u << 16);
}
__device__ __forceinline__ float bf_hi(unsigned u) {
    return __uint_as_float(u & 0xffff0000u);
}

// P[t][n][o] = sum_c x[n][t][c] * conv_w[o][c], stored bf16 (128B rows).
// Block 0 pre-converts w_ih/w_hh to bf16 and precomputes the folded gate
// bias (b_ih + b_hh + conv_b @ w_ih^T).
__global__ __launch_bounds__(256) void proj_kernel(
    const float* __restrict__ x, const float* __restrict__ conv_w,
    const float* __restrict__ conv_b, const float* __restrict__ w_ih,
    const float* __restrict__ w_hh, const float* __restrict__ b_ih,
    const float* __restrict__ b_hh,
    __hip_bfloat16* __restrict__ P, unsigned short* __restrict__ wihb,
    unsigned short* __restrict__ whhb, float* __restrict__ biasT)
{
    const int tid = threadIdx.x;
    if (blockIdx.x == 0) {   // prep block
        for (int e = tid; e < 4 * OO * OO; e += 256) {
            wihb[e] = (unsigned short)cvt_rne(w_ih[e]);
            whhb[e] = (unsigned short)cvt_rne(w_hh[e]);
        }
        float bj = b_ih[tid] + b_hh[tid];
        #pragma unroll
        for (int o = 0; o < OO; o += 4) {
            float4 cb = *(const float4*)(conv_b + o);
            float4 wr = *(const float4*)(w_ih + (size_t)tid * OO + o);
            bj = fmaf(cb.x, wr.x, bj); bj = fmaf(cb.y, wr.y, bj);
            bj = fmaf(cb.z, wr.z, bj); bj = fmaf(cb.w, wr.w, bj);
        }
        biasT[tid] = bj;
        return;
    }
    const int lane = tid & 63;
    const int wv = tid >> 6;
    float w[CC];
    #pragma unroll
    for (int c = 0; c < CC; c += 4) {
        float4 v = *(const float4*)(conv_w + lane * CC + c);
        w[c] = v.x; w[c + 1] = v.y; w[c + 2] = v.z; w[c + 3] = v.w;
    }
    const int rbase = (blockIdx.x - 1) * 16 + wv * 4;
    #pragma unroll
    for (int i = 0; i < 4; ++i) {
        int r = rbase + i;                    // r = n*TT + t (x row order)
        const float* xr = x + (size_t)r * CC;
        float a0 = 0.f, a1 = 0.f;
        #pragma unroll
        for (int c = 0; c < CC; c += 8) {
            float4 v = *(const float4*)(xr + c);
            float4 u = *(const float4*)(xr + c + 4);
            a0 = fmaf(v.x, w[c], a0);     a0 = fmaf(v.y, w[c + 1], a0);
            a0 = fmaf(v.z, w[c + 2], a0); a0 = fmaf(v.w, w[c + 3], a0);
            a1 = fmaf(u.x, w[c + 4], a1); a1 = fmaf(u.y, w[c + 5], a1);
            a1 = fmaf(u.z, w[c + 6], a1); a1 = fmaf(u.w, w[c + 7], a1);
        }
        int n = r / TT;
        int t = r - n * TT;
        ((unsigned short*)P)[(((size_t)t << 11) + n) * OO + lane] =
            (unsigned short)cvt_rne(a0 + a1);
    }
}

// Pure gather-max kernel (round-0 proven version): 4 rows/wave, dwordx2
// per lane, full-grid (2560 blocks) so random L2 loads are latency-hidden
// by occupancy. XCD-swizzled block ids keep each t-slab L2-local.
__global__ __launch_bounds__(256, 4) void gather_kernel(
    const __hip_bfloat16* __restrict__ P, const int* __restrict__ A,
    unsigned* __restrict__ featw)
{
    __shared__ int A_sh[4][128];            // per-wave: 4 rows x 32 idx
    const int tid = threadIdx.x;
    const int lane = tid & 63;
    const int wv = tid >> 6;
    const int bs = (blockIdx.x & 7) * 320 + (blockIdx.x >> 3);  // XCD swizzle
    const int r0 = bs << 4;                 // 16 rows/block, r = t*NA + n
    const int t = r0 >> 11;                 // block never crosses a t-slab
    const unsigned short* Pt = (const unsigned short*)P + ((size_t)t << 17);

    const int rw = r0 + wv * 4;             // wave's first row
    // stage this wave's 4 A-rows (128 ints) wave-locally; same-wave DS
    // ordering makes the later reads safe without a barrier.
    ((int2*)A_sh[wv])[lane] = ((const int2*)(A + ((size_t)rw << 5)))[lane];

    const int i_row = lane >> 4;            // 0..3: row within wave
    const int oc8 = lane & 15;              // 8B chunk (4 channels)
    const char* plane = (const char*)Pt + oc8 * 8;
    const int* myA = &A_sh[wv][i_row * 32];

    const int nself = (rw + i_row) & (NA - 1);
    const uint2 su = *(const uint2*)(plane + ((size_t)nself << 7));

    float m0 = -INFINITY, m1 = -INFINITY, m2 = -INFINITY, m3 = -INFINITY;
    #pragma unroll
    for (int bb = 0; bb < 2; ++bb) {
        int idx[16];
        #pragma unroll
        for (int g = 0; g < 16; ++g)        // broadcast ds_read_b32
            idx[g] = myA[bb * 16 + g];
        uint2 uv[16];                       // 32 VGPRs in-flight payload
        #pragma unroll
        for (int g = 0; g < 16; ++g)
            uv[g] = *(const uint2*)(plane + ((size_t)idx[g] << 7));
        #pragma unroll
        for (int g = 0; g < 16; ++g) {
            m0 = fmaxf(m0, bf_lo(uv[g].x)); m1 = fmaxf(m1, bf_hi(uv[g].x));
            m2 = fmaxf(m2, bf_lo(uv[g].y)); m3 = fmaxf(m3, bf_hi(uv[g].y));
        }
    }
    uint2 pk;
    pk.x = pack2(m0 - bf_lo(su.x), m1 - bf_hi(su.x));
    pk.y = pack2(m2 - bf_lo(su.y), m3 - bf_hi(su.y));
    *(uint2*)&featw[((size_t)(rw + i_row) << 5) + oc8 * 2] = pk;
}

// LSTM, channel-slice wave layout: wave wv computes gate tiles
// {i,f,g,o} x (cols wv*16..wv*16+15), so lane l holds all 4 gates of
// agent (l>>4)*4+rg at channel wv*16+(l&15) -> pointwise fully
// in-register (no gate-plane LDS exchange). Per step: ONE barrier;
// h_sh double-buffered (write (t+1)&1, read t&1) so the single barrier
// is race-free. feat A-frags prefetched from global one step ahead.
__global__ __launch_bounds__(256) void lstm_kernel(
    const unsigned short* __restrict__ feat,
    const unsigned short* __restrict__ wihb,
    const unsigned short* __restrict__ whhb,
    const float* __restrict__ biasT, float* __restrict__ out)
{
    const int tid = threadIdx.x;
    const int lane = tid & 63;
    const int wv = tid >> 6;          // channel slice
    const int l15 = lane & 15;
    const int q = lane >> 4;
    const int a0 = blockIdx.x * 16;
    const int ch = wv * 16 + l15;     // this lane's gate/hidden channel

    // B-frags: gate g tile needs w rows g*64+ch (bf16, preconverted).
    short8 bfI[4][2], bfH[4][2];
    #pragma unroll
    for (int g = 0; g < 4; ++g) {
        int row = g * 64 + ch;
        #pragma unroll
        for (int ks = 0; ks < 2; ++ks) {
            bfI[g][ks] =
                *(const short8*)(wihb + ((size_t)row << 6) + ks * 32 + q * 8);
            bfH[g][ks] =
                *(const short8*)(whhb + ((size_t)row << 6) + ks * 32 + q * 8);
        }
    }
    float bias_g[4];
    #pragma unroll
    for (int g = 0; g < 4; ++g)
        bias_g[g] = biasT[g * 64 + ch];

    __shared__ __align__(16) unsigned short h_sh[2][16 * 72];  // dbuf, pad 72

    // zero h_sh[0]
    for (int e = tid; e < 16 * 72 / 2; e += 256)
        ((unsigned*)h_sh[0])[e] = 0u;

    float cst[4] = {0.f, 0.f, 0.f, 0.f};

    // preload feat A-frags for t = 0 (row = agent a0+l15)
    short8 ff[2];
    #pragma unroll
    for (int ks = 0; ks < 2; ++ks)
        ff[ks] = *(const short8*)(
            feat + (((size_t)a0 + l15) << 6) + ks * 32 + q * 8);

    __syncthreads();  // h_sh[0] ready

    for (int t = 0; t < TT; ++t) {
        // A-frag of h from the current buffer
        short8 ah[2];
        #pragma unroll
        for (int ks = 0; ks < 2; ++ks)
            ah[ks] = *(const short8*)(
                &h_sh[t & 1][l15 * 72 + ks * 32 + q * 8]);

        float4v acc[4] = {{0.f, 0.f, 0.f, 0.f}, {0.f, 0.f, 0.f, 0.f},
                          {0.f, 0.f, 0.f, 0.f}, {0.f, 0.f, 0.f, 0.f}};
        #pragma unroll
        for (int ks = 0; ks < 2; ++ks) {
            #pragma unroll
            for (int g = 0; g < 4; ++g) {
                acc[g] = __builtin_amdgcn_mfma_f32_16x16x32_bf16(
                    ff[ks], bfI[g][ks], acc[g], 0, 0, 0);
                acc[g] = __builtin_amdgcn_mfma_f32_16x16x32_bf16(
                    ah[ks], bfH[g][ks], acc[g], 0, 0, 0);
            }
        }

        // prefetch next step's feat frags while MFMAs drain
        short8 ffn[2];
        int tn = (t + 1 < TT) ? t + 1 : t;
        #pragma unroll
        for (int ks = 0; ks < 2; ++ks)
            ffn[ks] = *(const short8*)(
                feat + ((((size_t)tn << 11) + a0 + l15) << 6) + ks * 32 + q * 8);

        // pointwise fully in-register: lane holds i/f/g/o for
        // agent q*4+rg at channel ch.
        #pragma unroll
        for (int rg = 0; rg < 4; ++rg) {
            float gi = acc[0][rg] + bias_g[0];
            float gf = acc[1][rg] + bias_g[1];
            float gz = acc[2][rg] + bias_g[2];
            float go = acc[3][rg] + bias_g[3];
            float ig = sigm(gi);
            float fg = sigm(gf);
            float zg = tanh_fast(gz);
            float og = sigm(go);
            cst[rg] = fmaf(fg, cst[rg], ig * zg);
            float hv = og * tanh_fast(cst[rg]);
            int agent = q * 4 + rg;
            h_sh[(t + 1) & 1][agent * 72 + ch] = (unsigned short)cvt_rne(hv);
            out[(((size_t)(a0 + agent) * TT + t) << 6) + ch] = hv;
            if (t == TT - 1) {
                size_t hb = (size_t)NA * TT * OO;
                out[hb + ((size_t)(a0 + agent) << 6) + ch] = hv;
                out[hb + ((size_t)NA << 6) + ((size_t)(a0 + agent) << 6) + ch] =
                    cst[rg];
            }
        }
        __syncthreads();  // h_sh[(t+1)&1] ready for everyone
        ff[0] = ffn[0]; ff[1] = ffn[1];
    }
}

extern "C" void kernel_launch(void* const* d_in, const int* in_sizes, int n_in,
                              void* d_out, int out_size, void* d_ws, size_t ws_size,
                              hipStream_t stream) {
    const float* x      = (const float*)d_in[0];
    const int*   A      = (const int*)  d_in[1];
    const float* conv_w = (const float*)d_in[2];
    const float* conv_b = (const float*)d_in[3];
    const float* w_ih   = (const float*)d_in[4];
    const float* w_hh   = (const float*)d_in[5];
    const float* b_ih   = (const float*)d_in[6];
    const float* b_hh   = (const float*)d_in[7];
    float* out = (float*)d_out;

    char* ws = (char*)d_ws;
    __hip_bfloat16* P  = (__hip_bfloat16*)ws;                    // 5.25 MB
    size_t offF = (size_t)TT * NA * OO * 2;
    unsigned* featw = (unsigned*)(ws + offF);                    // 5.25 MB
    size_t offW = offF + (size_t)TT * NA * OO * 2;
    unsigned short* wihb = (unsigned short*)(ws + offW);         // 32 KB
    unsigned short* whhb = wihb + 4 * OO * OO;                   // 32 KB
    float* biasT = (float*)(whhb + 4 * OO * OO);                 // 1 KB

    hipLaunchKernelGGL(proj_kernel, dim3(NA * TT / 16 + 1), dim3(256), 0, stream,
                       x, conv_w, conv_b, w_ih, w_hh, b_ih, b_hh,
                       P, wihb, whhb, biasT);
    hipLaunchKernelGGL(gather_kernel, dim3(NA * TT / 16), dim3(256), 0, stream,
                       P, A, featw);
    hipLaunchKernelGGL(lstm_kernel, dim3(NA / 16), dim3(256), 0, stream,
                       (const unsigned short*)featw, wihb, whhb, biasT, out);
}